// Round 2
// baseline (189.794 us; speedup 1.0000x reference)
//
#include <hip/hip_runtime.h>

#define BATCH 8192
#define DIM 1024
#define HEADS 8
#define HEAD_DIM 128
#define DSTATE 256

typedef __attribute__((ext_vector_type(8))) short short8v;   // 8 bf16 (4 VGPRs)
typedef __attribute__((ext_vector_type(4))) float f32x4;
typedef __attribute__((ext_vector_type(4))) unsigned short ushort4v;

__device__ __forceinline__ unsigned short f2bf(float x) {
  unsigned int u = __builtin_bit_cast(unsigned int, x);
  unsigned int r = u + 0x7FFFu + ((u >> 16) & 1u);   // RNE
  return (unsigned short)(r >> 16);
}
__device__ __forceinline__ float bf2f(unsigned short h) {
  unsigned int u = ((unsigned int)h) << 16;
  return __builtin_bit_cast(float, u);
}

// ---------- precompute: A_bar (f32) and coef=(A_bar-1)/A ----------
__global__ void pc_params(const float* __restrict__ logdt,
                          const float* __restrict__ arelog,
                          const float* __restrict__ aim,
                          float* __restrict__ abr, float* __restrict__ abi,
                          float* __restrict__ cre, float* __restrict__ cim) {
  int i = blockIdx.x * 256 + threadIdx.x;            // 2048 = H*N
  float ld = logdt[i];
  float dt = log1pf(expf(ld));                       // softplus
  float Ar = -expf(arelog[i]);
  float Ai = aim[i];
  float e  = expf(dt * Ar);
  float th = dt * Ai;
  float Abr = e * cosf(th), Abi = e * sinf(th);
  abr[i] = Abr; abi[i] = Abi;
  float den = Ar * Ar + Ai * Ai;
  float br = Abr - 1.0f;
  cre[i] = (br * Ar + Abi * Ai) / den;
  cim[i] = (Abi * Ar - br * Ai) / den;
}

// ---------- W1 = coef * B  (bf16, layout (H,N,P)) ----------
__global__ void pc_w1(const float* __restrict__ Bre, const float* __restrict__ Bim,
                      const float* __restrict__ cre, const float* __restrict__ cim,
                      unsigned short* __restrict__ w1re, unsigned short* __restrict__ w1im) {
  int i = blockIdx.x * 256 + threadIdx.x;            // 262144 = H*N*P
  int hn = i >> 7;
  float cr = cre[hn], ci = cim[hn];
  float br = Bre[i], bi = Bim[i];
  w1re[i] = f2bf(cr * br - ci * bi);
  w1im[i] = f2bf(cr * bi + ci * br);
}

// ---------- W2 = C_re, -C_im  (bf16, layout (H,P,N)) ----------
__global__ void pc_w2(const float* __restrict__ Cre, const float* __restrict__ Cim,
                      unsigned short* __restrict__ w2re, unsigned short* __restrict__ w2mi) {
  int i = blockIdx.x * 256 + threadIdx.x;            // 262144 = H*P*N
  w2re[i] = f2bf(Cre[i]);
  w2mi[i] = f2bf(-Cim[i]);
}

// ---------- RMSNorm -> x_hat bf16 (one wave per row) ----------
__global__ __launch_bounds__(256) void rms_k(const float* __restrict__ xt,
                                             const float* __restrict__ w,
                                             unsigned short* __restrict__ xbf) {
  int wid = threadIdx.x >> 6, lane = threadIdx.x & 63;
  int row = blockIdx.x * 4 + wid;
  const float* xr = xt + (long)row * DIM;
  f32x4 v[4];
  float ssq = 0.f;
  #pragma unroll
  for (int c = 0; c < 4; ++c) {
    v[c] = *(const f32x4*)(xr + c * 256 + lane * 4);
    ssq += v[c][0]*v[c][0] + v[c][1]*v[c][1] + v[c][2]*v[c][2] + v[c][3]*v[c][3];
  }
  #pragma unroll
  for (int m = 1; m < 64; m <<= 1) ssq += __shfl_xor(ssq, m, 64);
  float sc = rsqrtf(ssq * (1.0f / DIM) + 1e-4f);
  unsigned short* orow = xbf + (long)row * DIM;
  #pragma unroll
  for (int c = 0; c < 4; ++c) {
    f32x4 w4 = *(const f32x4*)(w + c * 256 + lane * 4);
    ushort4v o;
    o[0] = f2bf(v[c][0] * sc * w4[0]);
    o[1] = f2bf(v[c][1] * sc * w4[1]);
    o[2] = f2bf(v[c][2] * sc * w4[2]);
    o[3] = f2bf(v[c][3] * sc * w4[3]);
    *(ushort4v*)(orow + c * 256 + lane * 4) = o;
  }
}

// ---------- main fused kernel ----------
// Grid: 1024 blocks = (8192/64 row-tiles) x 8 heads, 256 threads = 4 waves.
// Each wave owns 16 batch rows (one MFMA b-tile) of one head. No barriers.
// GEMM1 swapped: D1[n][b] = W1[n][p] * xhat^T[p][b]
// GEMM2 swapped: D2[p][b] = [Cre|-Cim][p][n] * ns^T[n][b]
__global__ __launch_bounds__(256) void s5_main(
    const unsigned short* __restrict__ xbf,
    const unsigned short* __restrict__ w1re, const unsigned short* __restrict__ w1im,
    const unsigned short* __restrict__ w2re, const unsigned short* __restrict__ w2mi,
    const float* __restrict__ abr, const float* __restrict__ abi,
    const float* __restrict__ sre, const float* __restrict__ sim,
    const float* __restrict__ xt, const float* __restrict__ dvec,
    float* __restrict__ out, float* __restrict__ nsre, float* __restrict__ nsim) {
  __shared__ float lds[4096];                        // 16KB: 4 waves x 4KB
  const int tid = threadIdx.x;
  const int wid = tid >> 6, lane = tid & 63;
  const int g = lane >> 4, bl = lane & 15;
  const int h = blockIdx.x & 7;
  const int rowbase = (blockIdx.x >> 3) * 64 + wid * 16;
  float* mylds = lds + wid * 1024;
  const int swz = (bl & 7) << 2;                     // XOR swizzle, keeps 16B align

  // x_hat B-fragments: 8 contiguous bf16 per lane, row = batch b (col of B)
  short8v xf[4];
  {
    const unsigned short* xrow = xbf + (rowbase + bl) * DIM + h * HEAD_DIM;
    #pragma unroll
    for (int ks = 0; ks < 4; ++ks)
      xf[ks] = *(const short8v*)(xrow + ks * 32 + g * 8);
  }

  f32x4 acc[8];
  #pragma unroll
  for (int pt = 0; pt < 8; ++pt) {
    f32x4 z = {0.f, 0.f, 0.f, 0.f};
    acc[pt] = z;
  }

  for (int kk = 0; kk < 8; ++kk) {                   // 32 states per iteration
    #pragma unroll
    for (int t = 0; t < 2; ++t) {
      const int nt = kk * 2 + t;
      const unsigned short* w1b  = w1re + (h * DSTATE + nt * 16 + bl) * HEAD_DIM + g * 8;
      const unsigned short* w1bi = w1im + (h * DSTATE + nt * 16 + bl) * HEAD_DIM + g * 8;
      short8v ar0 = *(const short8v*)(w1b);
      short8v ar1 = *(const short8v*)(w1b + 32);
      short8v ar2 = *(const short8v*)(w1b + 64);
      short8v ar3 = *(const short8v*)(w1b + 96);
      short8v ai0 = *(const short8v*)(w1bi);
      short8v ai1 = *(const short8v*)(w1bi + 32);
      short8v ai2 = *(const short8v*)(w1bi + 64);
      short8v ai3 = *(const short8v*)(w1bi + 96);
      const int nidx = nt * 16 + g * 4;
      const f32x4 Ar = *(const f32x4*)(abr + h * DSTATE + nidx);
      const f32x4 Ai = *(const f32x4*)(abi + h * DSTATE + nidx);
      f32x4 dr = {0.f, 0.f, 0.f, 0.f};
      f32x4 di = {0.f, 0.f, 0.f, 0.f};
      dr = __builtin_amdgcn_mfma_f32_16x16x32_bf16(ar0, xf[0], dr, 0, 0, 0);
      dr = __builtin_amdgcn_mfma_f32_16x16x32_bf16(ar1, xf[1], dr, 0, 0, 0);
      dr = __builtin_amdgcn_mfma_f32_16x16x32_bf16(ar2, xf[2], dr, 0, 0, 0);
      dr = __builtin_amdgcn_mfma_f32_16x16x32_bf16(ar3, xf[3], dr, 0, 0, 0);
      di = __builtin_amdgcn_mfma_f32_16x16x32_bf16(ai0, xf[0], di, 0, 0, 0);
      di = __builtin_amdgcn_mfma_f32_16x16x32_bf16(ai1, xf[1], di, 0, 0, 0);
      di = __builtin_amdgcn_mfma_f32_16x16x32_bf16(ai2, xf[2], di, 0, 0, 0);
      di = __builtin_amdgcn_mfma_f32_16x16x32_bf16(ai3, xf[3], di, 0, 0, 0);
      // elementwise complex recurrence: ns = A_bar*state + Bx
      const int b = rowbase + bl;
      const int so = (b * HEADS + h) * DSTATE + nidx;
      const f32x4 sr4 = *(const f32x4*)(sre + so);
      const f32x4 si4 = *(const f32x4*)(sim + so);
      f32x4 nr, ni;
      #pragma unroll
      for (int r = 0; r < 4; ++r) {
        nr[r] = fmaf(Ar[r], sr4[r], fmaf(-Ai[r], si4[r], dr[r]));
        ni[r] = fmaf(Ar[r], si4[r], fmaf(Ai[r], sr4[r], di[r]));
      }
      *(f32x4*)(nsre + so) = nr;
      *(f32x4*)(nsim + so) = ni;
      // stash in per-wave LDS chunk for the lane-transpose to GEMM2 B-frags
      float* lp = mylds + bl * 32 + ((t * 16 + g * 4) ^ swz);
      *(f32x4*)lp = nr;
      *(f32x4*)(lp + 512) = ni;
    }
    // GEMM2 B-fragments: lane needs 8 consecutive n of its own b row
    short8v pbr, pbi;
    {
      const float* lp = mylds + bl * 32;
      const int w0 = (g * 8) ^ swz;
      const int w1o = (g * 8 + 4) ^ swz;
      f32x4 r0 = *(const f32x4*)(lp + w0);
      f32x4 r1 = *(const f32x4*)(lp + w1o);
      f32x4 i0 = *(const f32x4*)(lp + 512 + w0);
      f32x4 i1 = *(const f32x4*)(lp + 512 + w1o);
      pbr[0] = (short)f2bf(r0[0]); pbr[1] = (short)f2bf(r0[1]);
      pbr[2] = (short)f2bf(r0[2]); pbr[3] = (short)f2bf(r0[3]);
      pbr[4] = (short)f2bf(r1[0]); pbr[5] = (short)f2bf(r1[1]);
      pbr[6] = (short)f2bf(r1[2]); pbr[7] = (short)f2bf(r1[3]);
      pbi[0] = (short)f2bf(i0[0]); pbi[1] = (short)f2bf(i0[1]);
      pbi[2] = (short)f2bf(i0[2]); pbi[3] = (short)f2bf(i0[3]);
      pbi[4] = (short)f2bf(i1[0]); pbi[5] = (short)f2bf(i1[1]);
      pbi[6] = (short)f2bf(i1[2]); pbi[7] = (short)f2bf(i1[3]);
    }
    // GEMM2 partial over this 32-state chunk
    const unsigned short* w2rb = w2re + (h * HEAD_DIM + bl) * DSTATE + kk * 32 + g * 8;
    const unsigned short* w2ib = w2mi + (h * HEAD_DIM + bl) * DSTATE + kk * 32 + g * 8;
    #pragma unroll
    for (int pt = 0; pt < 8; ++pt) {
      short8v a2r = *(const short8v*)(w2rb + pt * 16 * DSTATE);
      short8v a2i = *(const short8v*)(w2ib + pt * 16 * DSTATE);
      acc[pt] = __builtin_amdgcn_mfma_f32_16x16x32_bf16(a2r, pbr, acc[pt], 0, 0, 0);
      acc[pt] = __builtin_amdgcn_mfma_f32_16x16x32_bf16(a2i, pbi, acc[pt], 0, 0, 0);
    }
  }
  // epilogue: out = x_t + 2*Ch + D*x_hat
  #pragma unroll
  for (int pt = 0; pt < 8; ++pt) {
    const int b = rowbase + bl;
    const int col = h * HEAD_DIM + pt * 16 + g * 4;
    const int o = b * DIM + col;
    const f32x4 xt4 = *(const f32x4*)(xt + o);
    const f32x4 d4 = *(const f32x4*)(dvec + col);
    ushort4v xh4 = *(const ushort4v*)(xbf + o);
    f32x4 ro;
    #pragma unroll
    for (int r = 0; r < 4; ++r)
      ro[r] = xt4[r] + 2.0f * acc[pt][r] + d4[r] * bf2f(xh4[r]);
    *(f32x4*)(out + o) = ro;
  }
}

extern "C" void kernel_launch(void* const* d_in, const int* in_sizes, int n_in,
                              void* d_out, int out_size, void* d_ws, size_t ws_size,
                              hipStream_t stream) {
  const float* x_t      = (const float*)d_in[0];
  const float* state_re = (const float*)d_in[1];
  const float* state_im = (const float*)d_in[2];
  const float* norm_w   = (const float*)d_in[3];
  const float* A_re_log = (const float*)d_in[4];
  const float* A_im     = (const float*)d_in[5];
  const float* B_re     = (const float*)d_in[6];
  const float* B_im     = (const float*)d_in[7];
  const float* C_re     = (const float*)d_in[8];
  const float* C_im     = (const float*)d_in[9];
  const float* Dv       = (const float*)d_in[10];
  const float* log_dt   = (const float*)d_in[11];

  float* out   = (float*)d_out;
  float* ns_re = out + (size_t)BATCH * DIM;
  float* ns_im = ns_re + (size_t)BATCH * HEADS * DSTATE;

  char* ws = (char*)d_ws;
  unsigned short* xbf  = (unsigned short*)ws;                       // 16 MB
  unsigned short* w1re = (unsigned short*)(ws + 16777216);          // 512 KB each
  unsigned short* w1im = w1re + 262144;
  unsigned short* w2re = w1im + 262144;
  unsigned short* w2mi = w2re + 262144;
  float* abr = (float*)(ws + 16777216 + 4 * 524288);
  float* abi = abr + 2048;
  float* cre = abi + 2048;
  float* cim = cre + 2048;

  pc_params<<<8, 256, 0, stream>>>(log_dt, A_re_log, A_im, abr, abi, cre, cim);
  pc_w1<<<1024, 256, 0, stream>>>(B_re, B_im, cre, cim, w1re, w1im);
  pc_w2<<<1024, 256, 0, stream>>>(C_re, C_im, w2re, w2mi);
  rms_k<<<2048, 256, 0, stream>>>(x_t, norm_w, xbf);
  s5_main<<<1024, 256, 0, stream>>>(xbf, w1re, w1im, w2re, w2mi, abr, abi,
                                    state_re, state_im, x_t, Dv, out, ns_re, ns_im);
}

// Round 3
// 127.069 us; speedup vs baseline: 1.4936x; 1.4936x over previous
//
#include <hip/hip_runtime.h>

#define BATCH 8192
#define DIM 1024
#define HEADS 8
#define HEAD_DIM 128
#define DSTATE 256

typedef __attribute__((ext_vector_type(8))) short short8v;   // 8 bf16 (4 VGPRs)
typedef __attribute__((ext_vector_type(4))) float f32x4;
typedef __attribute__((ext_vector_type(4))) unsigned short ushort4v;

__device__ __forceinline__ unsigned short f2bf(float x) {
  unsigned int u = __builtin_bit_cast(unsigned int, x);
  unsigned int r = u + 0x7FFFu + ((u >> 16) & 1u);   // RNE
  return (unsigned short)(r >> 16);
}
__device__ __forceinline__ float bf2f(unsigned short h) {
  unsigned int u = ((unsigned int)h) << 16;
  return __builtin_bit_cast(float, u);
}

// ---------- precompute: A_bar (f32) and coef=(A_bar-1)/A ----------
__global__ void pc_params(const float* __restrict__ logdt,
                          const float* __restrict__ arelog,
                          const float* __restrict__ aim,
                          float* __restrict__ abr, float* __restrict__ abi,
                          float* __restrict__ cre, float* __restrict__ cim) {
  int i = blockIdx.x * 256 + threadIdx.x;            // 2048 = H*N
  float ld = logdt[i];
  float dt = log1pf(expf(ld));                       // softplus
  float Ar = -expf(arelog[i]);
  float Ai = aim[i];
  float e  = expf(dt * Ar);
  float th = dt * Ai;
  float Abr = e * cosf(th), Abi = e * sinf(th);
  abr[i] = Abr; abi[i] = Abi;
  float den = Ar * Ar + Ai * Ai;
  float br = Abr - 1.0f;
  cre[i] = (br * Ar + Abi * Ai) / den;
  cim[i] = (Abi * Ar - br * Ai) / den;
}

// ---------- W1 = coef * B  (bf16, layout (H,N,P)) ----------
__global__ void pc_w1(const float* __restrict__ Bre, const float* __restrict__ Bim,
                      const float* __restrict__ cre, const float* __restrict__ cim,
                      unsigned short* __restrict__ w1re, unsigned short* __restrict__ w1im) {
  int i = blockIdx.x * 256 + threadIdx.x;            // 262144 = H*N*P
  int hn = i >> 7;
  float cr = cre[hn], ci = cim[hn];
  float br = Bre[i], bi = Bim[i];
  w1re[i] = f2bf(cr * br - ci * bi);
  w1im[i] = f2bf(cr * bi + ci * br);
}

// ---------- W2 = C_re, -C_im  (bf16, layout (H,P,N)) ----------
__global__ void pc_w2(const float* __restrict__ Cre, const float* __restrict__ Cim,
                      unsigned short* __restrict__ w2re, unsigned short* __restrict__ w2mi) {
  int i = blockIdx.x * 256 + threadIdx.x;            // 262144 = H*P*N
  w2re[i] = f2bf(Cre[i]);
  w2mi[i] = f2bf(-Cim[i]);
}

// ---------- RMSNorm -> x_hat bf16 (one wave per row) ----------
__global__ __launch_bounds__(256) void rms_k(const float* __restrict__ xt,
                                             const float* __restrict__ w,
                                             unsigned short* __restrict__ xbf) {
  int wid = threadIdx.x >> 6, lane = threadIdx.x & 63;
  int row = blockIdx.x * 4 + wid;
  const float* xr = xt + (long)row * DIM;
  f32x4 v[4];
  float ssq = 0.f;
  #pragma unroll
  for (int c = 0; c < 4; ++c) {
    v[c] = *(const f32x4*)(xr + c * 256 + lane * 4);
    ssq += v[c][0]*v[c][0] + v[c][1]*v[c][1] + v[c][2]*v[c][2] + v[c][3]*v[c][3];
  }
  #pragma unroll
  for (int m = 1; m < 64; m <<= 1) ssq += __shfl_xor(ssq, m, 64);
  float sc = rsqrtf(ssq * (1.0f / DIM) + 1e-4f);
  unsigned short* orow = xbf + (long)row * DIM;
  #pragma unroll
  for (int c = 0; c < 4; ++c) {
    f32x4 w4 = *(const f32x4*)(w + c * 256 + lane * 4);
    ushort4v o;
    o[0] = f2bf(v[c][0] * sc * w4[0]);
    o[1] = f2bf(v[c][1] * sc * w4[1]);
    o[2] = f2bf(v[c][2] * sc * w4[2]);
    o[3] = f2bf(v[c][3] * sc * w4[3]);
    *(ushort4v*)(orow + c * 256 + lane * 4) = o;
  }
}

// ---------- main fused kernel: register-resident weights ----------
// Grid: 1024 blocks = 8 heads x 128, 512 threads = 8 waves.
// Wave w owns: GEMM1 n-slice [32w,32w+32) (W1 slice in regs, 64 VGPR)
//              GEMM2 p-tile  [16w,16w+16) (W2 slice in regs, 64 VGPR)
// Block grid-strides over 4 tiles of 16 batch rows. Software-pipelined:
//   iter t: issue loads(t) -> GEMM2+epilogue(t-1) -> GEMM1+recur+LDS(t) -> barrier
// LDS: double-buffered bf16 P-matrix [2][2][16b][256n], XOR swizzle (bl&7)<<3.
__global__ __launch_bounds__(512, 2) void s5_main(
    const unsigned short* __restrict__ xbf,
    const unsigned short* __restrict__ w1re, const unsigned short* __restrict__ w1im,
    const unsigned short* __restrict__ w2re, const unsigned short* __restrict__ w2mi,
    const float* __restrict__ abr, const float* __restrict__ abi,
    const float* __restrict__ sre, const float* __restrict__ sim,
    const float* __restrict__ xt, const float* __restrict__ dvec,
    float* __restrict__ out, float* __restrict__ nsre, float* __restrict__ nsim) {
  __shared__ unsigned short PB[2][2][16][256];       // 32 KB
  const int tid = threadIdx.x;
  const int w = tid >> 6, lane = tid & 63;
  const int g = lane >> 4, bl = lane & 15;
  const int h = blockIdx.x & 7;
  const int blk = blockIdx.x >> 3;                   // 0..127
  const int sw = (bl & 7) << 3;                      // n-index XOR swizzle
  const int TILES = 4;

  // ---- weights -> registers (once per block) ----
  short8v w1r[2][4], w1i[2][4];
  #pragma unroll
  for (int t = 0; t < 2; ++t) {
    const int nt = w * 2 + t;
    const unsigned short* pr = w1re + (h * DSTATE + nt * 16 + bl) * HEAD_DIM + g * 8;
    const unsigned short* pi = w1im + (h * DSTATE + nt * 16 + bl) * HEAD_DIM + g * 8;
    #pragma unroll
    for (int ks = 0; ks < 4; ++ks) {
      w1r[t][ks] = *(const short8v*)(pr + ks * 32);
      w1i[t][ks] = *(const short8v*)(pi + ks * 32);
    }
  }
  short8v w2r[8], w2i[8];
  {
    const unsigned short* qr = w2re + (h * HEAD_DIM + w * 16 + bl) * DSTATE + g * 8;
    const unsigned short* qi = w2mi + (h * HEAD_DIM + w * 16 + bl) * DSTATE + g * 8;
    #pragma unroll
    for (int kk = 0; kk < 8; ++kk) {
      w2r[kk] = *(const short8v*)(qr + kk * 32);
      w2i[kk] = *(const short8v*)(qi + kk * 32);
    }
  }
  f32x4 Arr[2], Aii[2];
  {
    const int nb = h * DSTATE + w * 32 + g * 4;
    Arr[0] = *(const f32x4*)(abr + nb);       Aii[0] = *(const f32x4*)(abi + nb);
    Arr[1] = *(const f32x4*)(abr + nb + 16);  Aii[1] = *(const f32x4*)(abi + nb + 16);
  }
  const f32x4 d4 = *(const f32x4*)(dvec + h * HEAD_DIM + w * 16 + g * 4);

  f32x4 xt4;           // epilogue prefetch (carried across iterations)
  ushort4v xh4;
  int prevO = 0;

  for (int ti = 0; ti <= TILES; ++ti) {
    short8v xf[4];
    f32x4 sr[2], si[2];
    int so0 = 0;
    if (ti < TILES) {
      const int rowbase = (blk * TILES + ti) * 16;
      const unsigned short* xrow = xbf + (rowbase + bl) * DIM + h * HEAD_DIM;
      #pragma unroll
      for (int ks = 0; ks < 4; ++ks)
        xf[ks] = *(const short8v*)(xrow + ks * 32 + g * 8);
      so0 = ((rowbase + bl) * HEADS + h) * DSTATE + w * 32 + g * 4;
      sr[0] = *(const f32x4*)(sre + so0);       si[0] = *(const f32x4*)(sim + so0);
      sr[1] = *(const f32x4*)(sre + so0 + 16);  si[1] = *(const f32x4*)(sim + so0 + 16);
    }
    if (ti > 0) {
      // ---- GEMM2 + epilogue for tile ti-1 ----
      const unsigned short (*pb)[16][256] = PB[(ti - 1) & 1];
      f32x4 a = {0.f, 0.f, 0.f, 0.f};
      #pragma unroll
      for (int kk = 0; kk < 8; ++kk) {
        short8v pbr = *(const short8v*)(&pb[0][bl][(kk * 32 + g * 8) ^ sw]);
        short8v pbi = *(const short8v*)(&pb[1][bl][(kk * 32 + g * 8) ^ sw]);
        a = __builtin_amdgcn_mfma_f32_16x16x32_bf16(w2r[kk], pbr, a, 0, 0, 0);
        a = __builtin_amdgcn_mfma_f32_16x16x32_bf16(w2i[kk], pbi, a, 0, 0, 0);
      }
      f32x4 ro;
      #pragma unroll
      for (int r = 0; r < 4; ++r)
        ro[r] = xt4[r] + 2.0f * a[r] + d4[r] * bf2f(xh4[r]);
      *(f32x4*)(out + prevO) = ro;
    }
    if (ti < TILES) {
      // ---- GEMM1 + recurrence + ns store + LDS write for tile ti ----
      #pragma unroll
      for (int t = 0; t < 2; ++t) {
        f32x4 dr = {0.f, 0.f, 0.f, 0.f};
        f32x4 di = {0.f, 0.f, 0.f, 0.f};
        dr = __builtin_amdgcn_mfma_f32_16x16x32_bf16(w1r[t][0], xf[0], dr, 0, 0, 0);
        dr = __builtin_amdgcn_mfma_f32_16x16x32_bf16(w1r[t][1], xf[1], dr, 0, 0, 0);
        dr = __builtin_amdgcn_mfma_f32_16x16x32_bf16(w1r[t][2], xf[2], dr, 0, 0, 0);
        dr = __builtin_amdgcn_mfma_f32_16x16x32_bf16(w1r[t][3], xf[3], dr, 0, 0, 0);
        di = __builtin_amdgcn_mfma_f32_16x16x32_bf16(w1i[t][0], xf[0], di, 0, 0, 0);
        di = __builtin_amdgcn_mfma_f32_16x16x32_bf16(w1i[t][1], xf[1], di, 0, 0, 0);
        di = __builtin_amdgcn_mfma_f32_16x16x32_bf16(w1i[t][2], xf[2], di, 0, 0, 0);
        di = __builtin_amdgcn_mfma_f32_16x16x32_bf16(w1i[t][3], xf[3], di, 0, 0, 0);
        f32x4 nr, ni;
        #pragma unroll
        for (int r = 0; r < 4; ++r) {
          nr[r] = fmaf(Arr[t][r], sr[t][r], fmaf(-Aii[t][r], si[t][r], dr[r]));
          ni[r] = fmaf(Arr[t][r], si[t][r], fmaf(Aii[t][r], sr[t][r], di[r]));
        }
        const int so = so0 + t * 16;
        *(f32x4*)(nsre + so) = nr;
        *(f32x4*)(nsim + so) = ni;
        ushort4v br, bi2;
        #pragma unroll
        for (int r = 0; r < 4; ++r) { br[r] = f2bf(nr[r]); bi2[r] = f2bf(ni[r]); }
        const int n0 = (w * 32 + t * 16 + g * 4) ^ sw;
        *(ushort4v*)(&PB[ti & 1][0][bl][n0]) = br;
        *(ushort4v*)(&PB[ti & 1][1][bl][n0]) = bi2;
      }
      // epilogue prefetch for this tile (consumed next iteration)
      const int rowbase = (blk * TILES + ti) * 16;
      const int o = (rowbase + bl) * DIM + h * HEAD_DIM + w * 16 + g * 4;
      xt4 = *(const f32x4*)(xt + o);
      xh4 = *(const ushort4v*)(xbf + o);
      prevO = o;
    }
    __syncthreads();
  }
}

extern "C" void kernel_launch(void* const* d_in, const int* in_sizes, int n_in,
                              void* d_out, int out_size, void* d_ws, size_t ws_size,
                              hipStream_t stream) {
  const float* x_t      = (const float*)d_in[0];
  const float* state_re = (const float*)d_in[1];
  const float* state_im = (const float*)d_in[2];
  const float* norm_w   = (const float*)d_in[3];
  const float* A_re_log = (const float*)d_in[4];
  const float* A_im     = (const float*)d_in[5];
  const float* B_re     = (const float*)d_in[6];
  const float* B_im     = (const float*)d_in[7];
  const float* C_re     = (const float*)d_in[8];
  const float* C_im     = (const float*)d_in[9];
  const float* Dv       = (const float*)d_in[10];
  const float* log_dt   = (const float*)d_in[11];

  float* out   = (float*)d_out;
  float* ns_re = out + (size_t)BATCH * DIM;
  float* ns_im = ns_re + (size_t)BATCH * HEADS * DSTATE;

  char* ws = (char*)d_ws;
  unsigned short* xbf  = (unsigned short*)ws;                       // 16 MB
  unsigned short* w1re = (unsigned short*)(ws + 16777216);          // 512 KB each
  unsigned short* w1im = w1re + 262144;
  unsigned short* w2re = w1im + 262144;
  unsigned short* w2mi = w2re + 262144;
  float* abr = (float*)(ws + 16777216 + 4 * 524288);
  float* abi = abr + 2048;
  float* cre = abi + 2048;
  float* cim = cre + 2048;

  pc_params<<<8, 256, 0, stream>>>(log_dt, A_re_log, A_im, abr, abi, cre, cim);
  pc_w1<<<1024, 256, 0, stream>>>(B_re, B_im, cre, cim, w1re, w1im);
  pc_w2<<<1024, 256, 0, stream>>>(C_re, C_im, w2re, w2mi);
  rms_k<<<2048, 256, 0, stream>>>(x_t, norm_w, xbf);
  s5_main<<<1024, 512, 0, stream>>>(xbf, w1re, w1im, w2re, w2mi, abr, abi,
                                    state_re, state_im, x_t, Dv, out, ns_re, ns_im);
}